// Round 4
// baseline (234.290 us; speedup 1.0000x reference)
//
#include <hip/hip_runtime.h>
#include <math.h>

// Histogram2D as i8 MFMA GEMM: hist[i][j] = sum_n wx[n][i]*wy[n][j].
// q = rint(w*320) (max 123 < 127), exact i32 accumulation; 8-bin window.
// ~41.6us of dur is the harness 0xAA poison of the 256MiB d_ws (measured:
// fillBufferAligned 6.46 TB/s, 81% peak — fixed floor). Reducible budget
// = ~43us (hist + reduce + dispatch overhead).
// R7: branch-free A&S erf. 86.1us.  R8: per-thread LDS clear + reduce grid
// 2x -> 84.5us (only -1.6; zeroing/reduce-chain were NOT critical path).
// R10 FAILED (+12.7us -> 97.2): atomicAdd slot-histograms. Lesson: 8.4M
// device-scope atomics (non-coherent per-XCD L2 -> far coherence point)
// cost ~+15us; extra tiny dispatch adds more. bf16 partials round-trip was
// the cheap design. Reverted.
// R11 (this round): fuse reduce INTO hist behind a software grid barrier.
//  - All 512 blocks exactly co-resident (2/CU, 68KiB LDS < 80, lb(512,4))
//    -> flags handshake is deadlock-safe.
//  - Writer: partial stores -> __threadfence (agent release, L2 writeback)
//    -> barrier -> per-block MAGIC flag (robust to ANY poison != MAGIC, no
//    init kernel needed — the R10 mistake).
//  - Reader: relaxed-poll one flag/thread under __syncthreads_and, then
//    __threadfence (invalidate) before cross-XCD partial reads.
//  - Kills the hist->reduce launch gap + reduce cold start. Predicted
//    84.5 -> ~79-82us; absmax unchanged (identical numerics).

#define NBINS   128
#define NB2     (NBINS * NBINS)
#define KC      256               // points per chunk
#define AX_B    32768             // bytes per axis staging: 128*256
#define THREADS 512
#define NBLOCKS 512               // 2 blocks/CU (68 KiB LDS each)
#define QSCALE  320.0f
#define MAGIC   0x13579BDFu

typedef int i32x4 __attribute__((ext_vector_type(4)));

static __device__ __forceinline__ unsigned short f2bf(float f) {
    unsigned int b = __float_as_uint(f);
    b += 0x7fff + ((b >> 16) & 1);            // RNE
    return (unsigned short)(b >> 16);
}
static __device__ __forceinline__ float bf2f(unsigned short u) {
    return __uint_as_float((unsigned int)u << 16);
}

// Abramowitz-Stegun 7.1.26: |err| <= 1.5e-7, branch-free.
// erf(x) = sign(x) * (1 - (a1 t + .. + a5 t^5) exp(-x^2)), t = 1/(1+p|x|)
static __device__ __forceinline__ float erf_fast(float x) {
    const float ax = fabsf(x);
    const float t  = __builtin_amdgcn_rcpf(fmaf(0.3275911f, ax, 1.0f));
    const float e  = __expf(-x * x);          // v_exp_f32; inf^2 -> e=0 safe
    float p = fmaf(1.061405429f, t, -1.453152027f);
    p = fmaf(p, t, 1.421413741f);
    p = fmaf(p, t, -0.284496736f);
    p = fmaf(p, t, 0.254829592f);
    p = p * t;
    return copysignf(fmaf(-p, e, 1.0f), x);
}

__global__ __launch_bounds__(THREADS, 4) void hist_fused_kernel(
    const float* __restrict__ x,
    const float* __restrict__ edges_x,
    const float* __restrict__ edges_y,
    unsigned short* __restrict__ partials,   // bf16 [block][16384]
    float* __restrict__ btot,                // f32 [512]
    unsigned int* __restrict__ flags,        // u32 [512]
    float* __restrict__ out,
    int n)
{
    // Staging element (bin b, point p), per axis:
    //   off = (b>>4)*4096 + (p>>6)*1024 + ((p>>4)&3)*256 + (b&15)*16 + (p&15)
    // Frag read (tile t, kstep s, lane l): t*4096 + s*1024 + l*16 ->
    // 16 contiguous bytes/lane, conflict-free (verified R3-R6).
    __shared__ __align__(16) signed char sh[2 * AX_B];   // 64 KiB
    __shared__ int xw[8];
    __shared__ float4 red[32][8];            // phase 2 (4 KiB)
    __shared__ float ws[8];
    __shared__ float stot;

    const int tid  = threadIdx.x;
    const int lane = tid & 63;
    const int wv   = tid >> 6;        // 0..7

    const float e0x = edges_x[0];
    const float dxw = edges_x[1] - e0x;
    const float e0y = edges_y[0];
    const float dyw = edges_y[1] - e0y;

    // scatter role: threads 0..255 axis x, 256..511 axis y, point = pl
    const int axis = tid >> 8;
    const int pl   = tid & 255;
    const float e0   = axis ? e0y : e0x;
    const float invd = 1.0f / (axis ? dyw : dxw);
    const float cc   = 0.7071067811865476f;   // 1/sqrt(2); bw = bin width
    signed char* const sdst =
        sh + axis * AX_B + (pl >> 6) * 1024 + ((pl >> 4) & 3) * 256 + (pl & 15);

    i32x4 acc[4][4];
    #pragma unroll
    for (int i = 0; i < 4; ++i)
        #pragma unroll
        for (int j = 0; j < 4; ++j)
            acc[i][j] = (i32x4){0, 0, 0, 0};

    const int rowQ = ((wv >> 1) & 1) * 4;  // 4x4 tile quadrant (16x16 tiles)
    const int colQ = (wv & 1) * 4;
    const int ks0  = (wv >> 2) * 2;        // K-split: waves 0-3 ksteps {0,1}, 4-7 {2,3}

    const int nchunks = (n + KC - 1) / KC;

    // preload chunk 0 and compute its q-bytes
    float u = 1e30f;
    {
        const int p = blockIdx.x * KC + pl;
        if (blockIdx.x < nchunks && p < n) u = x[(size_t)p * 6 + axis];
    }
    int b0;
    signed char qv[8];
    {
        const float spos = (u - e0) * invd;
        int b = (int)floorf(spos + 0.5f) - 4;
        b0 = b < 0 ? 0 : (b > NBINS - 8 ? NBINS - 8 : b);
        const float t0 = ((float)b0 - spos) * cc;
        float z[9];
        #pragma unroll
        for (int k = 0; k < 9; ++k) z[k] = erf_fast(t0 + (float)k * cc);
        #pragma unroll
        for (int k = 0; k < 8; ++k)
            qv[k] = (signed char)(int)rintf(0.5f * (z[k + 1] - z[k]) * QSCALE);
    }
    int oldb0 = b0;   // first iter clears zeros onto already-zero bytes: harmless

    // one-time staging zero (R8)
    {
        float4* zp = (float4*)sh;
        #pragma unroll
        for (int i = 0; i < 8; ++i)
            zp[tid + i * THREADS] = (float4){0.f, 0.f, 0.f, 0.f};
    }
    __syncthreads();

    for (int chunk = blockIdx.x; chunk < nchunks; chunk += gridDim.x) {
        // prefetch next chunk's coordinate (hide HBM latency)
        const int nchunk = chunk + gridDim.x;
        float un = 1e30f;
        if (nchunk < nchunks) {
            const int pn = nchunk * KC + pl;
            if (pn < n) un = x[(size_t)pn * 6 + axis];
        }

        // clear previous chunk's 8 bytes, then write this chunk's 8.
        // Column is thread-private; same-thread DS ops are program-ordered,
        // so overlapping old/new ranges resolve correctly.
        #pragma unroll
        for (int k = 0; k < 8; ++k) {
            const int b = oldb0 + k;
            sdst[(b >> 4) * 4096 + (b & 15) * 16] = 0;
        }
        #pragma unroll
        for (int k = 0; k < 8; ++k) {
            const int b = b0 + k;
            sdst[(b >> 4) * 4096 + (b & 15) * 16] = qv[k];
        }
        __syncthreads();

        // MFMA phase; next chunk's erf/q interleaves on the VALU pipe
        #pragma unroll
        for (int s = 0; s < 2; ++s) {
            const int ks = ks0 + s;
            i32x4 av[4], bv[4];
            #pragma unroll
            for (int i = 0; i < 4; ++i)
                av[i] = *(const i32x4*)(sh + (rowQ + i) * 4096 + ks * 1024 + lane * 16);
            #pragma unroll
            for (int j = 0; j < 4; ++j)
                bv[j] = *(const i32x4*)(sh + AX_B + (colQ + j) * 4096 + ks * 1024 + lane * 16);
            #pragma unroll
            for (int i = 0; i < 4; ++i)
                #pragma unroll
                for (int j = 0; j < 4; ++j)
                    acc[i][j] = __builtin_amdgcn_mfma_i32_16x16x64_i8(
                        av[i], bv[j], acc[i][j], 0, 0, 0);
        }

        {   // compute next chunk's q-bytes (overlaps MFMA/ds_read latency)
            oldb0 = b0;
            const float spos = (un - e0) * invd;
            int b = (int)floorf(spos + 0.5f) - 4;
            b0 = b < 0 ? 0 : (b > NBINS - 8 ? NBINS - 8 : b);
            const float t0 = ((float)b0 - spos) * cc;
            float z[9];
            #pragma unroll
            for (int k = 0; k < 9; ++k) z[k] = erf_fast(t0 + (float)k * cc);
            #pragma unroll
            for (int k = 0; k < 8; ++k)
                qv[k] = (signed char)(int)rintf(0.5f * (z[k + 1] - z[k]) * QSCALE);
        }
        __syncthreads();
    }

    // epilogue: merge K-split wave pairs (exact i32), then scale & store bf16.
    // C/D layout col=lane&15, row=(lane>>4)*4+reg (shape-determined).
    if (wv >= 4) {
        int* dst = (int*)sh + (wv - 4) * 4096;
        #pragma unroll
        for (int i = 0; i < 4; ++i)
            #pragma unroll
            for (int j = 0; j < 4; ++j)
                #pragma unroll
                for (int g = 0; g < 4; ++g)
                    dst[((i * 4 + j) * 4 + g) * 64 + lane] = acc[i][j][g];
    }
    __syncthreads();

    int bsum = 0;
    if (wv < 4) {
        const float qs = 1.0f / (QSCALE * QSCALE);
        const int* src = (const int*)sh + wv * 4096;
        unsigned short* my = partials + (size_t)blockIdx.x * NB2;
        const int r0 = (lane >> 4) * 4;
        const int c0 = lane & 15;
        #pragma unroll
        for (int i = 0; i < 4; ++i)
            #pragma unroll
            for (int j = 0; j < 4; ++j)
                #pragma unroll
                for (int g = 0; g < 4; ++g) {
                    const int v = acc[i][j][g] + src[((i * 4 + j) * 4 + g) * 64 + lane];
                    bsum += v;
                    const int row = (rowQ + i) * 16 + r0 + g;
                    const int col = (colQ + j) * 16 + c0;
                    my[row * NBINS + col] = f2bf((float)v * qs);
                }
    }
    // block total (exact i32 within wave)
    #pragma unroll
    for (int off = 32; off > 0; off >>= 1) bsum += __shfl_down(bsum, off, 64);
    if (lane == 0) xw[wv] = bsum;
    __syncthreads();
    if (tid == 0) {
        const float qs = 1.0f / (QSCALE * QSCALE);
        btot[blockIdx.x] = (float)(xw[0] + xw[1] + xw[2] + xw[3]) * qs;
    }

    // ---- software grid barrier (all 512 blocks co-resident by construction)
    __threadfence();                         // agent release: flush partials/btot
    __syncthreads();
    if (tid == 0)
        __hip_atomic_store(&flags[blockIdx.x], MAGIC,
                           __ATOMIC_RELAXED, __HIP_MEMORY_SCOPE_AGENT);
    int ok;
    do {
        const unsigned int v = __hip_atomic_load(&flags[tid],
                                   __ATOMIC_RELAXED, __HIP_MEMORY_SCOPE_AGENT);
        ok = (v == MAGIC);
    } while (!__syncthreads_and(ok));
    __threadfence();                         // acquire: invalidate stale lines

    // ---- phase 2: reduce + normalize. Block covers bins [b*32, b*32+32).
    // grand total
    float tl = btot[tid];
    #pragma unroll
    for (int off = 32; off > 0; off >>= 1) tl += __shfl_down(tl, off, 64);
    if ((tid & 63) == 0) ws[tid >> 6] = tl;

    const int binBase = blockIdx.x * 32;
    if (tid < 256) {
        const int g = tid >> 3;              // 0..31: group of 16 partials
        const int q = tid & 7;               // 0..7: quad of 4 bins
        float4 s = {0.f, 0.f, 0.f, 0.f};
        #pragma unroll 4
        for (int k = 0; k < 16; ++k) {
            const int pidx = g * 16 + k;
            const ushort4 v = *(const ushort4*)(partials +
                                (size_t)pidx * NB2 + binBase + q * 4);
            s.x += bf2f(v.x); s.y += bf2f(v.y); s.z += bf2f(v.z); s.w += bf2f(v.w);
        }
        red[g][q] = s;
    }
    __syncthreads();

    if (tid == 0) {
        float tot = 0.f;
        #pragma unroll
        for (int k = 0; k < 8; ++k) tot += ws[k];
        stot = 1.0f / (tot * dxw * dyw);
    }
    __syncthreads();

    if (tid < 8) {
        float4 a = red[0][tid];
        #pragma unroll
        for (int g = 1; g < 32; ++g) {
            const float4 b = red[g][tid];
            a.x += b.x; a.y += b.y; a.z += b.z; a.w += b.w;
        }
        const float sc = stot;
        a.x *= sc; a.y *= sc; a.z *= sc; a.w *= sc;
        *(float4*)(out + binBase + tid * 4) = a;
    }
}

extern "C" void kernel_launch(void* const* d_in, const int* in_sizes, int n_in,
                              void* d_out, int out_size, void* d_ws, size_t ws_size,
                              hipStream_t stream)
{
    const float* x  = (const float*)d_in[0];
    const float* ex = (const float*)d_in[1];
    const float* ey = (const float*)d_in[2];
    float* out = (float*)d_out;
    const int n = in_sizes[0] / 6;

    unsigned short* partials = (unsigned short*)d_ws;             // 512*16384 bf16
    float* btot = (float*)((char*)d_ws + (size_t)NBLOCKS * NB2 * 2);  // 512 f32
    unsigned int* flags = (unsigned int*)(btot + NBLOCKS);            // 512 u32

    hist_fused_kernel<<<NBLOCKS, THREADS, 0, stream>>>(
        x, ex, ey, partials, btot, flags, out, n);
}

// Round 9
// 85.115 us; speedup vs baseline: 2.7526x; 2.7526x over previous
//
#include <hip/hip_runtime.h>
#include <math.h>

// Histogram2D as i8 MFMA GEMM: hist[i][j] = sum_n wx[n][i]*wy[n][j].
// q = rint(w*320) (max 123 < 127), exact i32 accumulation; 8-bin window.
// ~41.6us of dur is the harness 0xAA poison of the 256MiB d_ws (fixed floor).
// R7: A&S erf 86.1us. R8: per-thread LDS clear + reduce grid 2x -> 84.5us.
// R10 FAILED (+12.7): device atomics -> far coherence point. R11 FAILED
// (+150): software grid barrier = 512x512 agent-scope spin loads thrash the
// coherence fabric. LESSON: never route through device-scope coherence here.
// R11 counters (diluted): MfmaUtil*dur ~= 3.2us (MFMA is ~12% of hist),
// bank-conflicts ~1100cyc/CU/chunk (minor), Occupancy 46% (64KiB LDS caps
// 2 blocks/CU = 16 waves). => hist is stall-bound; 16 waves can't hide the
// 2-barrier/chunk lockstep.
// R12: 100% occupancy, same algorithm.
//  - KC 256->128: staging LDS 64->32 KiB.
//  - THREADS 512->1024 (16 waves), NBLOCKS=512 -> 2 blocks/CU but now
//    32 waves/CU (100%). Partials stay 512x32KiB=16MiB; reduce unchanged.
//  - Re-tile: 16 waves x (2x2 tiles), full K per wave -> acc 16 VGPR, no
//    K-split merge; __launch_bounds__(1024,8) forces <=64 VGPR.
//  - x-prefetch issued after bar1 -> vmcnt drain off the barrier path.
// R13-R16: resubmit unchanged (benches failed on acquisition; no data).
// Predicted: hist ~30 -> ~18-22us, total 84.5 -> ~74-78us. If neutral:
// hist is per-CU serial-LDS/barrier-bound -> next: staging width / erf LUT.

#define NBINS   128
#define NB2     (NBINS * NBINS)
#define KC      128               // points per chunk
#define AX_B    16384             // bytes per axis staging: 128 bins * 128 pts
#define THREADS 1024
#define NBLOCKS 512               // 2 blocks/CU, 32 waves/CU
#define QSCALE  320.0f

typedef int i32x4 __attribute__((ext_vector_type(4)));

static __device__ __forceinline__ unsigned short f2bf(float f) {
    unsigned int b = __float_as_uint(f);
    b += 0x7fff + ((b >> 16) & 1);            // RNE
    return (unsigned short)(b >> 16);
}
static __device__ __forceinline__ float bf2f(unsigned short u) {
    return __uint_as_float((unsigned int)u << 16);
}

// Abramowitz-Stegun 7.1.26: |err| <= 1.5e-7, branch-free.
static __device__ __forceinline__ float erf_fast(float x) {
    const float ax = fabsf(x);
    const float t  = __builtin_amdgcn_rcpf(fmaf(0.3275911f, ax, 1.0f));
    const float e  = __expf(-x * x);          // v_exp_f32; inf^2 -> e=0 safe
    float p = fmaf(1.061405429f, t, -1.453152027f);
    p = fmaf(p, t, 1.421413741f);
    p = fmaf(p, t, -0.284496736f);
    p = fmaf(p, t, 0.254829592f);
    p = p * t;
    return copysignf(fmaf(-p, e, 1.0f), x);
}

__global__ __launch_bounds__(THREADS, 8) void hist_mfma_kernel(
    const float* __restrict__ x,
    const float* __restrict__ edges_x,
    const float* __restrict__ edges_y,
    unsigned short* __restrict__ partials,   // bf16 [block][16384]
    float* __restrict__ btot,
    int n)
{
    // Staging element (bin b, point p), per axis (now 128 pts):
    //   off = (b>>4)*2048 + (p>>6)*1024 + ((p>>4)&3)*256 + (b&15)*16 + (p&15)
    // Frag read (tile t, kstep s, lane l): t*2048 + s*1024 + l*16 ->
    // 16 contiguous bytes/lane, conflict-free (same inner math as R3-R6,
    // only the bin-group stride changed 4096->2048).
    __shared__ __align__(16) signed char sh[2 * AX_B];   // 32 KiB
    __shared__ int xw[16];

    const int tid  = threadIdx.x;
    const int lane = tid & 63;
    const int wv   = tid >> 6;        // 0..15

    const float e0x = edges_x[0];
    const float dxw = edges_x[1] - e0x;
    const float e0y = edges_y[0];
    const float dyw = edges_y[1] - e0y;

    // scatter role: threads 0..127 axis x, 128..255 axis y (waves 0..3);
    // waves 4..15 have no staging/erf role.
    const bool isrole = (wv < 4);
    const int axis = (tid >> 7) & 1;
    const int pl   = tid & 127;
    const float e0   = axis ? e0y : e0x;
    const float invd = 1.0f / (axis ? dyw : dxw);
    const float cc   = 0.7071067811865476f;   // 1/sqrt(2); bw = bin width
    signed char* const sdst =
        sh + axis * AX_B + (pl >> 6) * 1024 + ((pl >> 4) & 3) * 256 + (pl & 15);

    // 16 waves x (2x2) 16x16 tiles, full K per wave.
    const int rowT = (wv & 3) * 2;    // tile rows rowT, rowT+1
    const int colT = (wv >> 2) * 2;   // tile cols colT, colT+1

    i32x4 acc[2][2];
    #pragma unroll
    for (int i = 0; i < 2; ++i)
        #pragma unroll
        for (int j = 0; j < 2; ++j)
            acc[i][j] = (i32x4){0, 0, 0, 0};

    const int nchunks = (n + KC - 1) / KC;

    // preload chunk 0 and compute its q-bytes (role threads only)
    int b0 = 0, oldb0 = 0;
    signed char qv[8];
    if (isrole) {
        float u = 1e30f;
        const int p = blockIdx.x * KC + pl;
        if (blockIdx.x < nchunks && p < n) u = x[(size_t)p * 6 + axis];
        const float spos = (u - e0) * invd;
        int b = (int)floorf(spos + 0.5f) - 4;
        b0 = b < 0 ? 0 : (b > NBINS - 8 ? NBINS - 8 : b);
        const float t0 = ((float)b0 - spos) * cc;
        float z[9];
        #pragma unroll
        for (int k = 0; k < 9; ++k) z[k] = erf_fast(t0 + (float)k * cc);
        #pragma unroll
        for (int k = 0; k < 8; ++k)
            qv[k] = (signed char)(int)rintf(0.5f * (z[k + 1] - z[k]) * QSCALE);
        oldb0 = b0;   // first-iter clear hits already-zero bytes: harmless
    }

    // one-time staging zero (32 KiB / 16 B / 1024 thr = 2 each)
    {
        float4* zp = (float4*)sh;
        zp[tid] = (float4){0.f, 0.f, 0.f, 0.f};
        zp[tid + THREADS] = (float4){0.f, 0.f, 0.f, 0.f};
    }
    __syncthreads();

    for (int chunk = blockIdx.x; chunk < nchunks; chunk += gridDim.x) {
        // clear previous chunk's 8 bytes, then write this chunk's 8.
        // Column is thread-private; same-thread DS ops are program-ordered.
        if (isrole) {
            #pragma unroll
            for (int k = 0; k < 8; ++k) {
                const int b = oldb0 + k;
                sdst[(b >> 4) * 2048 + (b & 15) * 16] = 0;
            }
            #pragma unroll
            for (int k = 0; k < 8; ++k) {
                const int b = b0 + k;
                sdst[(b >> 4) * 2048 + (b & 15) * 16] = qv[k];
            }
        }
        __syncthreads();

        // prefetch next chunk's coordinate AFTER the barrier: its vmcnt
        // drains at first use (erf below), never on a barrier path.
        float un = 1e30f;
        const int nchunk = chunk + gridDim.x;
        if (isrole && nchunk < nchunks) {
            const int pn = nchunk * KC + pl;
            if (pn < n) un = x[(size_t)pn * 6 + axis];
        }

        // MFMA phase: 2 ksteps x (2x2 tiles) = 8 MFMA/wave/chunk
        #pragma unroll
        for (int s = 0; s < 2; ++s) {
            i32x4 av[2];
            #pragma unroll
            for (int i = 0; i < 2; ++i)
                av[i] = *(const i32x4*)(sh + (rowT + i) * 2048 + s * 1024 + lane * 16);
            #pragma unroll
            for (int j = 0; j < 2; ++j) {
                const i32x4 bv = *(const i32x4*)(sh + AX_B + (colT + j) * 2048 + s * 1024 + lane * 16);
                #pragma unroll
                for (int i = 0; i < 2; ++i)
                    acc[i][j] = __builtin_amdgcn_mfma_i32_16x16x64_i8(
                        av[i], bv, acc[i][j], 0, 0, 0);
            }
        }

        // compute next chunk's q-bytes (role waves; overlaps others' MFMA)
        if (isrole) {
            oldb0 = b0;
            const float spos = (un - e0) * invd;
            int b = (int)floorf(spos + 0.5f) - 4;
            b0 = b < 0 ? 0 : (b > NBINS - 8 ? NBINS - 8 : b);
            const float t0 = ((float)b0 - spos) * cc;
            float z[9];
            #pragma unroll
            for (int k = 0; k < 9; ++k) z[k] = erf_fast(t0 + (float)k * cc);
            #pragma unroll
            for (int k = 0; k < 8; ++k)
                qv[k] = (signed char)(int)rintf(0.5f * (z[k + 1] - z[k]) * QSCALE);
        }
        __syncthreads();
    }

    // epilogue: each wave owns full-K acc for its 2x2 tiles -> direct store.
    // C/D layout col=lane&15, row=(lane>>4)*4+reg (shape-determined).
    int bsum = 0;
    {
        const float qs = 1.0f / (QSCALE * QSCALE);
        unsigned short* my = partials + (size_t)blockIdx.x * NB2;
        const int r0 = (lane >> 4) * 4;
        const int c0 = lane & 15;
        #pragma unroll
        for (int i = 0; i < 2; ++i)
            #pragma unroll
            for (int j = 0; j < 2; ++j)
                #pragma unroll
                for (int g = 0; g < 4; ++g) {
                    const int v = acc[i][j][g];
                    bsum += v;
                    const int row = (rowT + i) * 16 + r0 + g;
                    const int col = (colT + j) * 16 + c0;
                    my[row * NBINS + col] = f2bf((float)v * qs);
                }
    }
    // block total (exact i32 within wave)
    #pragma unroll
    for (int off = 32; off > 0; off >>= 1) bsum += __shfl_down(bsum, off, 64);
    if (lane == 0) xw[wv] = bsum;
    __syncthreads();
    if (tid == 0) {
        const float qs = 1.0f / (QSCALE * QSCALE);
        int s = 0;
        #pragma unroll
        for (int k = 0; k < 16; ++k) s += xw[k];
        btot[blockIdx.x] = (float)s * qs;
    }
}

// Fused reduction + normalize: 256 blocks x 256 threads (R8 structure).
// Block B covers bins [B*64, B*64+64). Thread t: bin4 = t&15 (4 bins),
// pgroup = t>>4 (32 partials each). Sums bf16 partials; normalizer from btot.
__global__ void reduce_kernel(const unsigned short* __restrict__ partials,
                              const float* __restrict__ btot,
                              const float* __restrict__ edges_x,
                              const float* __restrict__ edges_y,
                              float* __restrict__ out)
{
    __shared__ float4 red[16][16];
    __shared__ float ws[4];
    __shared__ float stot;

    const int t = threadIdx.x;
    const int bin4 = t & 15;
    const int pg = t >> 4;
    const int binBase = blockIdx.x * 64;

    // grand total (redundant per block; btot is 2KB, L2-hot)
    float tl = btot[t] + btot[t + 256];
    #pragma unroll
    for (int off = 32; off > 0; off >>= 1) tl += __shfl_down(tl, off, 64);
    if ((t & 63) == 0) ws[t >> 6] = tl;

    // sum 32 partials for 4 bins
    const unsigned short* p =
        partials + (size_t)(pg * 32) * NB2 + binBase + bin4 * 4;
    float4 s = {0.f, 0.f, 0.f, 0.f};
    #pragma unroll 8
    for (int k = 0; k < 32; ++k) {
        const ushort4 v = *(const ushort4*)(p + (size_t)k * NB2);
        s.x += bf2f(v.x); s.y += bf2f(v.y); s.z += bf2f(v.z); s.w += bf2f(v.w);
    }
    red[pg][bin4] = s;
    __syncthreads();

    if (t == 0) {
        const float dxw = edges_x[1] - edges_x[0];
        const float dyw = edges_y[1] - edges_y[0];
        stot = 1.0f / ((ws[0] + ws[1] + ws[2] + ws[3]) * dxw * dyw);
    }
    __syncthreads();

    if (t < 16) {
        float4 a = red[0][t];
        #pragma unroll
        for (int g = 1; g < 16; ++g) {
            const float4 b = red[g][t];
            a.x += b.x; a.y += b.y; a.z += b.z; a.w += b.w;
        }
        a.x *= stot; a.y *= stot; a.z *= stot; a.w *= stot;
        *(float4*)(out + binBase + t * 4) = a;
    }
}

extern "C" void kernel_launch(void* const* d_in, const int* in_sizes, int n_in,
                              void* d_out, int out_size, void* d_ws, size_t ws_size,
                              hipStream_t stream)
{
    const float* x  = (const float*)d_in[0];
    const float* ex = (const float*)d_in[1];
    const float* ey = (const float*)d_in[2];
    float* out = (float*)d_out;
    const int n = in_sizes[0] / 6;

    unsigned short* partials = (unsigned short*)d_ws;             // 512*16384 bf16
    float* btot = (float*)((char*)d_ws + (size_t)NBLOCKS * NB2 * 2);  // 512 f32

    hist_mfma_kernel<<<NBLOCKS, THREADS, 0, stream>>>(x, ex, ey, partials, btot, n);
    reduce_kernel<<<NB2 / 64, 256, 0, stream>>>(partials, btot, ex, ey, out);
}

// Round 10
// 81.911 us; speedup vs baseline: 2.8603x; 1.0391x over previous
//
#include <hip/hip_runtime.h>
#include <math.h>

// Histogram2D, sparse formulation (R17): each point adds its exact-i32
// 8x8 window outer-product qx[i]*qy[j] into a per-block LDS histogram via
// LDS atomics (CU-local; R10's device-scope-coherence lesson does NOT
// apply). Replaces the i8 MFMA GEMM which multiplied 99.6% zeros
// (128x128 computed vs 8x8 useful per point) and whose staging/barrier
// structure carried a ~25us residue no pipe model explained:
//  - R8 (8 waves, KC=256) 84.5us == R12 (16 waves, KC=128, 100% occ)
//    85.1us -> cost scales with work, not occupancy, not chunk count.
//  - MfmaUtil*dur ~3.2us, LDS model ~5-10us, erf ~2us, loads ~2us.
// Numerics IDENTICAL to the GEMM path: same A&S erf, same q=rint(w*320),
// exact i32 accumulation, bf16 partials, same reduce kernel -> absmax
// should stay ~0.00098. ~41.6us of dur is the harness 0xAA poison of the
// 256MiB d_ws (fixed floor). Predicted: hist ~35 -> 10-14us, total -> 62-68.
// Failure reads: neutral -> shared bottleneck is x-load path; much worse ->
// hot-bin atomic serialization, revert R8.
// LDS hist stride 129 i32: bank = (bx0+by0+c) % 32 (129%32=1) ~ uniform;
// 64.5 KiB/block -> 2 blocks/CU (129 KiB < 160). All 64 atomic offsets are
// compile-time imm (i*129+j)*4 <= 3640 < 64K off one base address.

#define NBINS   128
#define NB2     (NBINS * NBINS)
#define LDH     129               // padded LDS row stride (i32)
#define THREADS 512
#define NBLOCKS 512
#define QSCALE  320.0f

static __device__ __forceinline__ unsigned short f2bf(float f) {
    unsigned int b = __float_as_uint(f);
    b += 0x7fff + ((b >> 16) & 1);            // RNE
    return (unsigned short)(b >> 16);
}
static __device__ __forceinline__ float bf2f(unsigned short u) {
    return __uint_as_float((unsigned int)u << 16);
}

// Abramowitz-Stegun 7.1.26: |err| <= 1.5e-7, branch-free.
static __device__ __forceinline__ float erf_fast(float x) {
    const float ax = fabsf(x);
    const float t  = __builtin_amdgcn_rcpf(fmaf(0.3275911f, ax, 1.0f));
    const float e  = __expf(-x * x);          // v_exp_f32; inf^2 -> e=0 safe
    float p = fmaf(1.061405429f, t, -1.453152027f);
    p = fmaf(p, t, 1.421413741f);
    p = fmaf(p, t, -0.284496736f);
    p = fmaf(p, t, 0.254829592f);
    p = p * t;
    return copysignf(fmaf(-p, e, 1.0f), x);
}

// Per-axis window: base bin b0 (clamped) + 8 quantized weights.
static __device__ __forceinline__ void axis_q(
    float u, float e0, float inv, int& b0, int q[8])
{
    const float cc = 0.7071067811865476f;     // 1/sqrt(2); bw = bin width
    const float spos = (u - e0) * inv;
    int b = (int)floorf(spos + 0.5f) - 4;
    b0 = b < 0 ? 0 : (b > NBINS - 8 ? NBINS - 8 : b);
    const float t0 = ((float)b0 - spos) * cc;
    float z[9];
    #pragma unroll
    for (int k = 0; k < 9; ++k) z[k] = erf_fast(t0 + (float)k * cc);
    #pragma unroll
    for (int k = 0; k < 8; ++k)
        q[k] = (int)rintf(0.5f * (z[k + 1] - z[k]) * QSCALE);
}

__global__ __launch_bounds__(THREADS, 4) void hist_sparse_kernel(
    const float* __restrict__ x,
    const float* __restrict__ edges_x,
    const float* __restrict__ edges_y,
    unsigned short* __restrict__ partials,   // bf16 [block][16384]
    float* __restrict__ btot,                // f32 [512]
    int n)
{
    __shared__ int lh[NBINS * LDH];          // 64.5 KiB
    __shared__ int xw[8];

    const int tid  = threadIdx.x;
    const int lane = tid & 63;
    const int wv   = tid >> 6;               // 0..7

    for (int i = tid; i < NBINS * LDH; i += THREADS) lh[i] = 0;

    const float e0x = edges_x[0];
    const float dxw = edges_x[1] - e0x;
    const float e0y = edges_y[0];
    const float dyw = edges_y[1] - e0y;
    const float ivx = 1.0f / dxw;
    const float ivy = 1.0f / dyw;
    __syncthreads();

    int bsum = 0;
    const int stride = gridDim.x * THREADS;
    for (int p = blockIdx.x * THREADS + tid; p < n; p += stride) {
        // both coordinates in one 8B load (p*24 is 8-aligned)
        const float2 u = *(const float2*)(x + (size_t)p * 6);
        int bx0, by0, qx[8], qy[8];
        axis_q(u.x, e0x, ivx, bx0, qx);
        axis_q(u.y, e0y, ivy, by0, qy);

        int sx = 0, sy = 0;
        #pragma unroll
        for (int k = 0; k < 8; ++k) { sx += qx[k]; sy += qy[k]; }
        bsum += sx * sy;                     // exact block total, no LDS re-read

        int* const base = lh + bx0 * LDH + by0;
        #pragma unroll
        for (int i = 0; i < 8; ++i) {
            const int qi = qx[i];
            #pragma unroll
            for (int j = 0; j < 8; ++j)
                atomicAdd(base + i * LDH + j, qi * qy[j]);
        }
    }
    __syncthreads();

    // epilogue: LDS i32 -> bf16 partials. Thread t: 32 consecutive bins
    // (64B contiguous global store as 8x ushort4); c+3 never crosses a row.
    {
        const float qs = 1.0f / (QSCALE * QSCALE);
        unsigned short* my = partials + (size_t)blockIdx.x * NB2;
        #pragma unroll
        for (int v = 0; v < 8; ++v) {
            const int e = tid * 32 + v * 4;
            const int r = e >> 7;
            const int c = e & 127;
            const int* row = lh + r * LDH + c;
            ushort4 o;
            o.x = f2bf((float)row[0] * qs);
            o.y = f2bf((float)row[1] * qs);
            o.z = f2bf((float)row[2] * qs);
            o.w = f2bf((float)row[3] * qs);
            *(ushort4*)(my + e) = o;
        }
    }

    // block total (exact i32 within wave; block sum ~1e8 << 2^31)
    #pragma unroll
    for (int off = 32; off > 0; off >>= 1) bsum += __shfl_down(bsum, off, 64);
    if (lane == 0) xw[wv] = bsum;
    __syncthreads();
    if (tid == 0) {
        const float qs = 1.0f / (QSCALE * QSCALE);
        int s = 0;
        #pragma unroll
        for (int k = 0; k < 8; ++k) s += xw[k];
        btot[blockIdx.x] = (float)s * qs;
    }
}

// Fused reduction + normalize (measured-good R8 structure, unchanged).
// 256 blocks x 256 threads. Block B covers bins [B*64, B*64+64).
// Thread t: bin4 = t&15 (4 bins), pgroup = t>>4 (32 partials each).
__global__ void reduce_kernel(const unsigned short* __restrict__ partials,
                              const float* __restrict__ btot,
                              const float* __restrict__ edges_x,
                              const float* __restrict__ edges_y,
                              float* __restrict__ out)
{
    __shared__ float4 red[16][16];
    __shared__ float ws[4];
    __shared__ float stot;

    const int t = threadIdx.x;
    const int bin4 = t & 15;
    const int pg = t >> 4;
    const int binBase = blockIdx.x * 64;

    // grand total (redundant per block; btot is 2KB, L2-hot)
    float tl = btot[t] + btot[t + 256];
    #pragma unroll
    for (int off = 32; off > 0; off >>= 1) tl += __shfl_down(tl, off, 64);
    if ((t & 63) == 0) ws[t >> 6] = tl;

    // sum 32 partials for 4 bins
    const unsigned short* p =
        partials + (size_t)(pg * 32) * NB2 + binBase + bin4 * 4;
    float4 s = {0.f, 0.f, 0.f, 0.f};
    #pragma unroll 8
    for (int k = 0; k < 32; ++k) {
        const ushort4 v = *(const ushort4*)(p + (size_t)k * NB2);
        s.x += bf2f(v.x); s.y += bf2f(v.y); s.z += bf2f(v.z); s.w += bf2f(v.w);
    }
    red[pg][bin4] = s;
    __syncthreads();

    if (t == 0) {
        const float dxw = edges_x[1] - edges_x[0];
        const float dyw = edges_y[1] - edges_y[0];
        stot = 1.0f / ((ws[0] + ws[1] + ws[2] + ws[3]) * dxw * dyw);
    }
    __syncthreads();

    if (t < 16) {
        float4 a = red[0][t];
        #pragma unroll
        for (int g = 1; g < 16; ++g) {
            const float4 b = red[g][t];
            a.x += b.x; a.y += b.y; a.z += b.z; a.w += b.w;
        }
        a.x *= stot; a.y *= stot; a.z *= stot; a.w *= stot;
        *(float4*)(out + binBase + t * 4) = a;
    }
}

extern "C" void kernel_launch(void* const* d_in, const int* in_sizes, int n_in,
                              void* d_out, int out_size, void* d_ws, size_t ws_size,
                              hipStream_t stream)
{
    const float* x  = (const float*)d_in[0];
    const float* ex = (const float*)d_in[1];
    const float* ey = (const float*)d_in[2];
    float* out = (float*)d_out;
    const int n = in_sizes[0] / 6;

    unsigned short* partials = (unsigned short*)d_ws;             // 512*16384 bf16
    float* btot = (float*)((char*)d_ws + (size_t)NBLOCKS * NB2 * 2);  // 512 f32

    hist_sparse_kernel<<<NBLOCKS, THREADS, 0, stream>>>(x, ex, ey, partials, btot, n);
    reduce_kernel<<<NB2 / 64, 256, 0, stream>>>(partials, btot, ex, ey, out);
}

// Round 11
// 76.388 us; speedup vs baseline: 3.0671x; 1.0723x over previous
//
#include <hip/hip_runtime.h>
#include <math.h>

// Histogram2D, sparse formulation (R17): each point adds its exact-i32
// 8x8 window outer-product qx[i]*qy[j] into a per-block LDS histogram via
// LDS atomics (CU-local). Replaced the i8 MFMA GEMM (99.6% zero multiplies).
// Ladder: R8 dense 84.5 -> R17 sparse 81.9 (best). Decomposition evidence:
// R11 showed inter-dispatch overhead ~0 -> hist+reduce = 40.3us, vs dense
// 42.9. Two disjoint algorithms within 2.6us => residue is SHARED costs:
// harness tiny-memset floor (per rocprof.md: dozens of reset() dispatches),
// 16MiB partials round-trip, cold x reads (poison fill thrashes L2/L3
// every iter). ~41.6us poison fill of 256MiB d_ws = fixed floor.
// R18 (this round): halve the partials round-trip. NBLOCKS 512->256,
// THREADS 512->1024 (same 262144 total threads, 16 waves/CU, LDS 64.5KiB
// = 1 block/CU). Partials 16->8MiB: hist writes -1.3us, reduce sums 16
// instead of 32 partials/bin (-2-3us). Predicted 81.9 -> 76-78.5; absmax
// unchanged. If only -1us: floor confirmed at ~fill+memsets+compute;
// next lever = atomic inner loop (u64 packing / f32 accum).
// Numerics: same A&S erf, q=rint(w*320), exact i32, bf16 partials.
// LDS hist stride 129 i32: bank = (bx0+by0+c) % 32 ~ uniform; all 64
// atomic offsets are compile-time imm (i*129+j)*4 off one base address.

#define NBINS   128
#define NB2     (NBINS * NBINS)
#define LDH     129               // padded LDS row stride (i32)
#define THREADS 1024
#define NBLOCKS 256
#define QSCALE  320.0f

static __device__ __forceinline__ unsigned short f2bf(float f) {
    unsigned int b = __float_as_uint(f);
    b += 0x7fff + ((b >> 16) & 1);            // RNE
    return (unsigned short)(b >> 16);
}
static __device__ __forceinline__ float bf2f(unsigned short u) {
    return __uint_as_float((unsigned int)u << 16);
}

// Abramowitz-Stegun 7.1.26: |err| <= 1.5e-7, branch-free.
static __device__ __forceinline__ float erf_fast(float x) {
    const float ax = fabsf(x);
    const float t  = __builtin_amdgcn_rcpf(fmaf(0.3275911f, ax, 1.0f));
    const float e  = __expf(-x * x);          // v_exp_f32; inf^2 -> e=0 safe
    float p = fmaf(1.061405429f, t, -1.453152027f);
    p = fmaf(p, t, 1.421413741f);
    p = fmaf(p, t, -0.284496736f);
    p = fmaf(p, t, 0.254829592f);
    p = p * t;
    return copysignf(fmaf(-p, e, 1.0f), x);
}

// Per-axis window: base bin b0 (clamped) + 8 quantized weights.
static __device__ __forceinline__ void axis_q(
    float u, float e0, float inv, int& b0, int q[8])
{
    const float cc = 0.7071067811865476f;     // 1/sqrt(2); bw = bin width
    const float spos = (u - e0) * inv;
    int b = (int)floorf(spos + 0.5f) - 4;
    b0 = b < 0 ? 0 : (b > NBINS - 8 ? NBINS - 8 : b);
    const float t0 = ((float)b0 - spos) * cc;
    float z[9];
    #pragma unroll
    for (int k = 0; k < 9; ++k) z[k] = erf_fast(t0 + (float)k * cc);
    #pragma unroll
    for (int k = 0; k < 8; ++k)
        q[k] = (int)rintf(0.5f * (z[k + 1] - z[k]) * QSCALE);
}

__global__ __launch_bounds__(THREADS, 4) void hist_sparse_kernel(
    const float* __restrict__ x,
    const float* __restrict__ edges_x,
    const float* __restrict__ edges_y,
    unsigned short* __restrict__ partials,   // bf16 [block][16384]
    float* __restrict__ btot,                // f32 [256]
    int n)
{
    __shared__ int lh[NBINS * LDH];          // 64.5 KiB
    __shared__ int xw[16];

    const int tid  = threadIdx.x;
    const int lane = tid & 63;
    const int wv   = tid >> 6;               // 0..15

    for (int i = tid; i < NBINS * LDH; i += THREADS) lh[i] = 0;

    const float e0x = edges_x[0];
    const float dxw = edges_x[1] - e0x;
    const float e0y = edges_y[0];
    const float dyw = edges_y[1] - e0y;
    const float ivx = 1.0f / dxw;
    const float ivy = 1.0f / dyw;
    __syncthreads();

    int bsum = 0;
    const int stride = gridDim.x * THREADS;
    for (int p = blockIdx.x * THREADS + tid; p < n; p += stride) {
        // both coordinates in one 8B load (p*24 is 8-aligned)
        const float2 u = *(const float2*)(x + (size_t)p * 6);
        int bx0, by0, qx[8], qy[8];
        axis_q(u.x, e0x, ivx, bx0, qx);
        axis_q(u.y, e0y, ivy, by0, qy);

        int sx = 0, sy = 0;
        #pragma unroll
        for (int k = 0; k < 8; ++k) { sx += qx[k]; sy += qy[k]; }
        bsum += sx * sy;                     // exact block total, no LDS re-read

        int* const base = lh + bx0 * LDH + by0;
        #pragma unroll
        for (int i = 0; i < 8; ++i) {
            const int qi = qx[i];
            #pragma unroll
            for (int j = 0; j < 8; ++j)
                atomicAdd(base + i * LDH + j, qi * qy[j]);
        }
    }
    __syncthreads();

    // epilogue: LDS i32 -> bf16 partials. Thread t: 16 consecutive bins
    // (32B contiguous global store as 4x ushort4); c+3 never crosses a row.
    {
        const float qs = 1.0f / (QSCALE * QSCALE);
        unsigned short* my = partials + (size_t)blockIdx.x * NB2;
        #pragma unroll
        for (int v = 0; v < 4; ++v) {
            const int e = tid * 16 + v * 4;
            const int r = e >> 7;
            const int c = e & 127;
            const int* row = lh + r * LDH + c;
            ushort4 o;
            o.x = f2bf((float)row[0] * qs);
            o.y = f2bf((float)row[1] * qs);
            o.z = f2bf((float)row[2] * qs);
            o.w = f2bf((float)row[3] * qs);
            *(ushort4*)(my + e) = o;
        }
    }

    // block total (exact i32 within wave; block sum ~2e8 << 2^31)
    #pragma unroll
    for (int off = 32; off > 0; off >>= 1) bsum += __shfl_down(bsum, off, 64);
    if (lane == 0) xw[wv] = bsum;
    __syncthreads();
    if (tid == 0) {
        const float qs = 1.0f / (QSCALE * QSCALE);
        int s = 0;
        #pragma unroll
        for (int k = 0; k < 16; ++k) s += xw[k];
        btot[blockIdx.x] = (float)s * qs;
    }
}

// Fused reduction + normalize: 256 blocks x 256 threads.
// Block B covers bins [B*64, B*64+64). Thread t: bin4 = t&15 (4 bins),
// pgroup = t>>4 (16 partials each, of 256 total).
__global__ void reduce_kernel(const unsigned short* __restrict__ partials,
                              const float* __restrict__ btot,
                              const float* __restrict__ edges_x,
                              const float* __restrict__ edges_y,
                              float* __restrict__ out)
{
    __shared__ float4 red[16][16];
    __shared__ float ws[4];
    __shared__ float stot;

    const int t = threadIdx.x;
    const int bin4 = t & 15;
    const int pg = t >> 4;
    const int binBase = blockIdx.x * 64;

    // grand total (redundant per block; btot is 1KB, L2-hot)
    float tl = btot[t];
    #pragma unroll
    for (int off = 32; off > 0; off >>= 1) tl += __shfl_down(tl, off, 64);
    if ((t & 63) == 0) ws[t >> 6] = tl;

    // sum 16 partials for 4 bins
    const unsigned short* p =
        partials + (size_t)(pg * 16) * NB2 + binBase + bin4 * 4;
    float4 s = {0.f, 0.f, 0.f, 0.f};
    #pragma unroll 8
    for (int k = 0; k < 16; ++k) {
        const ushort4 v = *(const ushort4*)(p + (size_t)k * NB2);
        s.x += bf2f(v.x); s.y += bf2f(v.y); s.z += bf2f(v.z); s.w += bf2f(v.w);
    }
    red[pg][bin4] = s;
    __syncthreads();

    if (t == 0) {
        const float dxw = edges_x[1] - edges_x[0];
        const float dyw = edges_y[1] - edges_y[0];
        stot = 1.0f / ((ws[0] + ws[1] + ws[2] + ws[3]) * dxw * dyw);
    }
    __syncthreads();

    if (t < 16) {
        float4 a = red[0][t];
        #pragma unroll
        for (int g = 1; g < 16; ++g) {
            const float4 b = red[g][t];
            a.x += b.x; a.y += b.y; a.z += b.z; a.w += b.w;
        }
        a.x *= stot; a.y *= stot; a.z *= stot; a.w *= stot;
        *(float4*)(out + binBase + t * 4) = a;
    }
}

extern "C" void kernel_launch(void* const* d_in, const int* in_sizes, int n_in,
                              void* d_out, int out_size, void* d_ws, size_t ws_size,
                              hipStream_t stream)
{
    const float* x  = (const float*)d_in[0];
    const float* ex = (const float*)d_in[1];
    const float* ey = (const float*)d_in[2];
    float* out = (float*)d_out;
    const int n = in_sizes[0] / 6;

    unsigned short* partials = (unsigned short*)d_ws;             // 256*16384 bf16
    float* btot = (float*)((char*)d_ws + (size_t)NBLOCKS * NB2 * 2);  // 256 f32

    hist_sparse_kernel<<<NBLOCKS, THREADS, 0, stream>>>(x, ex, ey, partials, btot, n);
    reduce_kernel<<<NB2 / 64, 256, 0, stream>>>(partials, btot, ex, ey, out);
}